// Round 1
// baseline (766.001 us; speedup 1.0000x reference)
//
#include <hip/hip_runtime.h>

// MusicLSTM: B=131072, E=13, I=13, H=64, G=4H=256 (torch gate order i,f,g,o).
// seq_len==1, h0=c0=0  =>  f-gate and W_hh are dead.
//   gates(e,h) = x[b,e,:] . W_ih[e,h,:] + b_ih[e,h] + b_hh[e,h]   (h in i,g,o rows only)
//   c = sigmoid(i)*tanh(g); hh = sigmoid(o)*tanh(c)
//   out[b,e] = sigmoid( sum_h hh*W_lin[e,h] + b_lin[e] )

#define E_N 13
#define I_N 13
#define H_N 64
#define G_N (4 * H_N)

__device__ __forceinline__ float fast_rcp(float x) { return __builtin_amdgcn_rcpf(x); }
__device__ __forceinline__ float fast_exp(float x) { return __expf(x); }          // v_exp_f32
__device__ __forceinline__ float sigmoid_f(float x) { return fast_rcp(1.0f + fast_exp(-x)); }
// tanh(x) = 1 - 2/(e^{2x}+1): safe at both tails (e^{2x}->inf => 1, ->0 => -1)
__device__ __forceinline__ float tanh_f(float x) { return 1.0f - 2.0f * fast_rcp(fast_exp(2.0f * x) + 1.0f); }

__global__ __launch_bounds__(256) void music_lstm_kernel(
    const float* __restrict__ x,     // [B][E][I]
    const float* __restrict__ W_ih,  // [E][G][I]
    const float* __restrict__ b_ih,  // [E][G]
    const float* __restrict__ b_hh,  // [E][G]
    const float* __restrict__ W_lin, // [E][H]
    const float* __restrict__ b_lin, // [E]
    float* __restrict__ out,         // [B][E]
    int n_b)
{
    int b = blockIdx.x * blockDim.x + threadIdx.x;
    if (b >= n_b) return;

    const float* xb = x + (size_t)b * (E_N * I_N);

    // e-loop is wave-uniform -> all W_ih/b_* accesses below have uniform
    // addresses -> compiler scalarizes them to s_load (constant cache),
    // keeping the inner loop pure v_fma_f32 with an SGPR operand.
    for (int e = 0; e < E_N; ++e) {
        float xv[I_N];
#pragma unroll
        for (int i = 0; i < I_N; ++i) xv[i] = xb[e * I_N + i];

        const float* We = W_ih + (size_t)e * (G_N * I_N);
        const float* bi = b_ih + e * G_N;
        const float* bh = b_hh + e * G_N;
        const float* wl = W_lin + e * H_N;

        float acc_out = b_lin[e];

#pragma unroll 2
        for (int h = 0; h < H_N; ++h) {
            // gate rows: i -> h, g -> 2H+h, o -> 3H+h  (f row H+h is dead)
            float ai = bi[h] + bh[h];
            float ag = bi[2 * H_N + h] + bh[2 * H_N + h];
            float ao = bi[3 * H_N + h] + bh[3 * H_N + h];
            const float* wi = We + (size_t)h * I_N;
            const float* wg = We + (size_t)(2 * H_N + h) * I_N;
            const float* wo = We + (size_t)(3 * H_N + h) * I_N;
#pragma unroll
            for (int i = 0; i < I_N; ++i) {
                ai = fmaf(xv[i], wi[i], ai);
                ag = fmaf(xv[i], wg[i], ag);
                ao = fmaf(xv[i], wo[i], ao);
            }
            float c = sigmoid_f(ai) * tanh_f(ag);
            float hh = sigmoid_f(ao) * tanh_f(c);
            acc_out = fmaf(hh, wl[h], acc_out);
        }

        out[(size_t)b * E_N + e] = sigmoid_f(acc_out);
    }
}

extern "C" void kernel_launch(void* const* d_in, const int* in_sizes, int n_in,
                              void* d_out, int out_size, void* d_ws, size_t ws_size,
                              hipStream_t stream) {
    const float* x     = (const float*)d_in[0];
    const float* W_ih  = (const float*)d_in[1];
    // d_in[2] = W_hh : dead (h0 = 0)
    const float* b_ih  = (const float*)d_in[3];
    const float* b_hh  = (const float*)d_in[4];
    const float* W_lin = (const float*)d_in[5];
    const float* b_lin = (const float*)d_in[6];
    float* out = (float*)d_out;

    int n_b = in_sizes[0] / (E_N * I_N);  // 131072
    int block = 256;
    int grid = (n_b + block - 1) / block;

    music_lstm_kernel<<<grid, block, 0, stream>>>(x, W_ih, b_ih, b_hh, W_lin, b_lin, out, n_b);
}

// Round 2
// 338.176 us; speedup vs baseline: 2.2651x; 2.2651x over previous
//
#include <hip/hip_runtime.h>

// MusicLSTM: B=131072, E=13, I=13, H=64, G=4H=256 (torch gate order i,f,g,o).
// seq_len==1, h0=c0=0  =>  f-gate and W_hh are dead.
//   gates(e,h) = x[b,e,:] . W_ih[e,h,:] + b_ih[e,h] + b_hh[e,h]   (h in i,g,o rows)
//   c = sigmoid(i)*tanh(g); hh = sigmoid(o)*tanh(c)
//   out[b,e] = sigmoid( sum_h hh*W_lin[e,h] + b_lin[e] )
//
// R1 lesson: 1 thread/batch-row -> 2048 waves = 25% occupancy cap, latency-bound
// (VALUBusy 31%, Occupancy 24.3%). Fix: gridDim.y = E so each block owns one
// block-uniform e -> 13x the waves (full occupancy) while W/bias addresses stay
// wave-uniform (scalarized s_load, VGPR=12 in R1).

#define E_N 13
#define I_N 13
#define H_N 64
#define G_N (4 * H_N)

__device__ __forceinline__ float fast_rcp(float x) { return __builtin_amdgcn_rcpf(x); }
__device__ __forceinline__ float fast_exp(float x) { return __expf(x); }          // v_exp_f32
__device__ __forceinline__ float sigmoid_f(float x) { return fast_rcp(1.0f + fast_exp(-x)); }
// tanh(x) = 1 - 2/(e^{2x}+1): safe at both tails (e^{2x}->inf => 1, ->0 => -1)
__device__ __forceinline__ float tanh_f(float x) { return 1.0f - 2.0f * fast_rcp(fast_exp(2.0f * x) + 1.0f); }

__global__ __launch_bounds__(256) void music_lstm_kernel(
    const float* __restrict__ x,     // [B][E][I]
    const float* __restrict__ W_ih,  // [E][G][I]
    const float* __restrict__ b_ih,  // [E][G]
    const float* __restrict__ b_hh,  // [E][G]
    const float* __restrict__ W_lin, // [E][H]
    const float* __restrict__ b_lin, // [E]
    float* __restrict__ out,         // [B][E]
    int n_b)
{
    const int b = blockIdx.x * blockDim.x + threadIdx.x;
    const int e = blockIdx.y;  // block-uniform -> all W/bias loads scalarize
    if (b >= n_b) return;

    // per-thread x row for this (b, e): 13 floats
    const float* xb = x + ((size_t)b * E_N + e) * I_N;
    float xv[I_N];
#pragma unroll
    for (int i = 0; i < I_N; ++i) xv[i] = xb[i];

    const float* We = W_ih + (size_t)e * (G_N * I_N);
    const float* bi = b_ih + e * G_N;
    const float* bh = b_hh + e * G_N;
    const float* wl = W_lin + e * H_N;

    float acc_out = b_lin[e];

#pragma unroll 2
    for (int h = 0; h < H_N; ++h) {
        // gate rows: i -> h, g -> 2H+h, o -> 3H+h  (f row H+h is dead)
        float ai = bi[h] + bh[h];
        float ag = bi[2 * H_N + h] + bh[2 * H_N + h];
        float ao = bi[3 * H_N + h] + bh[3 * H_N + h];
        const float* wi = We + (size_t)h * I_N;
        const float* wg = We + (size_t)(2 * H_N + h) * I_N;
        const float* wo = We + (size_t)(3 * H_N + h) * I_N;
#pragma unroll
        for (int i = 0; i < I_N; ++i) {
            ai = fmaf(xv[i], wi[i], ai);
            ag = fmaf(xv[i], wg[i], ag);
            ao = fmaf(xv[i], wo[i], ao);
        }
        float c = sigmoid_f(ai) * tanh_f(ag);
        float hh = sigmoid_f(ao) * tanh_f(c);
        acc_out = fmaf(hh, wl[h], acc_out);
    }

    out[(size_t)b * E_N + e] = sigmoid_f(acc_out);
}

extern "C" void kernel_launch(void* const* d_in, const int* in_sizes, int n_in,
                              void* d_out, int out_size, void* d_ws, size_t ws_size,
                              hipStream_t stream) {
    const float* x     = (const float*)d_in[0];
    const float* W_ih  = (const float*)d_in[1];
    // d_in[2] = W_hh : dead (h0 = 0)
    const float* b_ih  = (const float*)d_in[3];
    const float* b_hh  = (const float*)d_in[4];
    const float* W_lin = (const float*)d_in[5];
    const float* b_lin = (const float*)d_in[6];
    float* out = (float*)d_out;

    const int n_b = in_sizes[0] / (E_N * I_N);  // 131072
    const int block = 256;
    dim3 grid((n_b + block - 1) / block, E_N);

    music_lstm_kernel<<<grid, block, 0, stream>>>(x, W_ih, b_ih, b_hh, W_lin, b_lin, out, n_b);
}

// Round 4
// 233.697 us; speedup vs baseline: 3.2778x; 1.4471x over previous
//
#include <hip/hip_runtime.h>

// MusicLSTM: B=131072, E=13, I=13, H=64, G=4H=256 (torch gate order i,f,g,o).
// seq_len==1, h0=c0=0  =>  f-gate and W_hh are dead.
// R2: VALU-issue-bound (VALUBusy 92%, MfmaUtil 0); gate GEMV = ~46% of slots.
// R4 (= R3 resubmit, acquisition timed out): move GEMV to the matrix pipe via
// mfma_f32_32x32x16_f16.
//   - per wave-iter: 32 batch rows, 6 MFMAs (i,g,o gates x 2 h-blocks), K=16
//   - bias (b_ih+b_hh) folded into k=13 of the MFMA (x side supplies 1.0)
//   - activations (remaining VALU work) unchanged from R2
//   - final 64-dot: per-lane partial + one shfl_xor(32) reduce
// Fragment layouts (32x32x16): A: lane l holds A[l&31][(l>>5)*8+j];
// B: B[(l>>5)*8+j][l&31]. Robustness: any k-permutation applied identically
// to A and B leaves the dot product invariant, so only A/B symmetry matters.
// C/D (HW-verified m74/m101): col=l&31, row=(r&3)+8*(r>>2)+4*(l>>5).

#define E_N 13
#define I_N 13
#define H_N 64
#define G_N 256
#define ROWS_PER_BLOCK 512  // 4 waves * 4 iters * 32 rows

typedef _Float16 half8 __attribute__((ext_vector_type(8)));
typedef float f32x16 __attribute__((ext_vector_type(16)));

__device__ __forceinline__ float fast_rcp(float x) { return __builtin_amdgcn_rcpf(x); }
__device__ __forceinline__ float fast_exp(float x) { return __expf(x); }          // v_exp_f32
__device__ __forceinline__ float sigmoid_f(float x) { return fast_rcp(1.0f + fast_exp(-x)); }
// tanh(x) = 1 - 2/(e^{2x}+1): safe at both tails
__device__ __forceinline__ float tanh_f(float x) { return 1.0f - 2.0f * fast_rcp(fast_exp(2.0f * x) + 1.0f); }

__global__ __launch_bounds__(256, 4) void music_lstm_mfma(
    const float* __restrict__ x,     // [B][E][I]
    const float* __restrict__ W_ih,  // [E][G][I]
    const float* __restrict__ b_ih,  // [E][G]
    const float* __restrict__ b_hh,  // [E][G]
    const float* __restrict__ W_lin, // [E][H]
    const float* __restrict__ b_lin, // [E]
    float* __restrict__ out,         // [B][E]
    int n_b)
{
    const int e     = blockIdx.x;        // e fastest -> all 13 e co-resident, L2/L3 line reuse
    const int tileb = blockIdx.y;
    const int tid   = threadIdx.x;
    const int lane  = tid & 63;
    const int wave  = tid >> 6;
    const int lrow  = lane & 31;         // gate row (A) / batch col (B, C/D)
    const int khalf = lane >> 5;         // k-group: lanes 0-31 -> k 0-7, 32-63 -> k 8-15
    const int koff  = khalf * 8;

    __shared__ float lds_wl[H_N];
    if (tid < H_N) lds_wl[tid] = W_lin[e * H_N + tid];
    __syncthreads();

    const float blin_e = b_lin[e];

    // --- W fragments (A operand), loaded once. wf[hb*3+g]: gate g in {i,g,o},
    // h-block hb in {0,1}. k=13 column carries the bias sum.
    half8 wf[6];
#pragma unroll
    for (int g = 0; g < 3; ++g) {
        const int gbase = (g == 0) ? 0 : (g == 1) ? 2 * H_N : 3 * H_N; // i,g,o (f dead)
#pragma unroll
        for (int hb = 0; hb < 2; ++hb) {
            const int row = gbase + hb * 32 + lrow;
            const float* wr = W_ih + ((size_t)e * G_N + row) * I_N;
            const float bias = b_ih[e * G_N + row] + b_hh[e * G_N + row];
            half8 f;
#pragma unroll
            for (int j = 0; j < 8; ++j) {
                const int k = koff + j;
                const float v = (k < I_N) ? wr[k] : ((k == I_N) ? bias : 0.0f);
                f[j] = (_Float16)v;
            }
            wf[hb * 3 + g] = f;
        }
    }

    const int b_wave = tileb * ROWS_PER_BLOCK + wave * 128;

    for (int it = 0; it < 4; ++it) {
        const int b0 = b_wave + it * 32;
        const int bb = (b0 + lrow < n_b) ? (b0 + lrow) : (n_b - 1);

        // --- x fragment (B operand): B[k][n], n = batch col = lrow
        const float* xb = x + (size_t)bb * (E_N * I_N) + e * I_N;
        half8 xf;
#pragma unroll
        for (int j = 0; j < 8; ++j) {
            const int k = koff + j;
            const float v = (k < I_N) ? xb[k] : ((k == I_N) ? 1.0f : 0.0f);
            xf[j] = (_Float16)v;
        }

        float partial = 0.0f;
#pragma unroll
        for (int hb = 0; hb < 2; ++hb) {
            f32x16 zz;
#pragma unroll
            for (int q = 0; q < 16; ++q) zz[q] = 0.0f;
            const f32x16 ai = __builtin_amdgcn_mfma_f32_32x32x16_f16(wf[hb * 3 + 0], xf, zz, 0, 0, 0);
            const f32x16 ag = __builtin_amdgcn_mfma_f32_32x32x16_f16(wf[hb * 3 + 1], xf, zz, 0, 0, 0);
            const f32x16 ao = __builtin_amdgcn_mfma_f32_32x32x16_f16(wf[hb * 3 + 2], xf, zz, 0, 0, 0);
#pragma unroll
            for (int r = 0; r < 16; ++r) {
                const int h = hb * 32 + (r & 3) + 8 * (r >> 2) + 4 * khalf;
                const float c  = sigmoid_f(ai[r]) * tanh_f(ag[r]);
                const float hh = sigmoid_f(ao[r]) * tanh_f(c);
                partial = fmaf(hh, lds_wl[h], partial);
            }
        }

        const float pre = partial + __shfl_xor(partial, 32) + blin_e;
        if (lane < 32 && b0 + lrow < n_b)
            out[(size_t)(b0 + lrow) * E_N + e] = sigmoid_f(pre);
    }
}

extern "C" void kernel_launch(void* const* d_in, const int* in_sizes, int n_in,
                              void* d_out, int out_size, void* d_ws, size_t ws_size,
                              hipStream_t stream) {
    const float* x     = (const float*)d_in[0];
    const float* W_ih  = (const float*)d_in[1];
    // d_in[2] = W_hh : dead (h0 = 0)
    const float* b_ih  = (const float*)d_in[3];
    const float* b_hh  = (const float*)d_in[4];
    const float* W_lin = (const float*)d_in[5];
    const float* b_lin = (const float*)d_in[6];
    float* out = (float*)d_out;

    const int n_b = in_sizes[0] / (E_N * I_N);  // 131072
    dim3 grid(E_N, (n_b + ROWS_PER_BLOCK - 1) / ROWS_PER_BLOCK);  // (13, 256)

    music_lstm_mfma<<<grid, 256, 0, stream>>>(x, W_ih, b_ih, b_hh, W_lin, b_lin, out, n_b);
}

// Round 5
// 226.393 us; speedup vs baseline: 3.3835x; 1.0323x over previous
//
#include <hip/hip_runtime.h>

// MusicLSTM: B=131072, E=13, I=13, H=64, G=4H=256 (torch gate order i,f,g,o).
// seq_len==1, h0=c0=0  =>  f-gate and W_hh are dead.
// R2: VALU-bound scalar (246us). R4: gate GEMV on MFMA pipe (137us) ->
// VALUBusy 68%, Occ 39% (= 4-wave/SIMD cap from 60 VGPR + 48 AGPR unified),
// FETCH 148MB (no cross-e L2 share), WRITE 47MB (no combining).
// R5: (1) grid swapped to (tileb=256, e=13): id = tileb+256e, 256%8==0 ->
//     all 13 e-blocks of a tileb on SAME XCD -> x reuse + write combine in L2.
//     (2) software-pipelined x prefetch (loads for it+1 issued before it's
//     epilogue; ~900cy HBM latency hides under ~2500cy activation math).
//     (3) trans 8->6 per h: sigma(a)*tanh(g) = (e^{2g}-1)/[(1+e^-a)(1+e^{2g})]
//     -> one rcp per product instead of two. Safe for |gate| <= 44.
// Fragment layouts (32x32x16): A: lane l holds A[l&31][(l>>5)*8+j];
// B: B[(l>>5)*8+j][l&31] (k-permutation applied identically to A and B is
// dot-invariant). C/D (HW-verified m74/m101): col=l&31, row=(r&3)+8(r>>2)+4(l>>5).

#define E_N 13
#define I_N 13
#define H_N 64
#define G_N 256
#define ROWS_PER_BLOCK 512  // 4 waves * 4 iters * 32 rows

typedef _Float16 half8 __attribute__((ext_vector_type(8)));
typedef float f32x16 __attribute__((ext_vector_type(16)));

__device__ __forceinline__ float fast_rcp(float x) { return __builtin_amdgcn_rcpf(x); }
__device__ __forceinline__ float fast_exp(float x) { return __expf(x); }  // v_exp_f32 path

__global__ __launch_bounds__(256, 4) void music_lstm_mfma(
    const float* __restrict__ x,     // [B][E][I]
    const float* __restrict__ W_ih,  // [E][G][I]
    const float* __restrict__ b_ih,  // [E][G]
    const float* __restrict__ b_hh,  // [E][G]
    const float* __restrict__ W_lin, // [E][H]
    const float* __restrict__ b_lin, // [E]
    float* __restrict__ out,         // [B][E]
    int n_b)
{
    const int tileb = blockIdx.x;    // fastest -> same-tileb e-blocks co-XCD
    const int e     = blockIdx.y;
    const int tid   = threadIdx.x;
    const int lane  = tid & 63;
    const int wave  = tid >> 6;
    const int lrow  = lane & 31;     // gate row (A) / batch col (B, C/D)
    const int khalf = lane >> 5;     // k-group: lanes 0-31 -> k 0-7, 32-63 -> k 8-15
    const int koff  = khalf * 8;

    __shared__ float lds_wl[H_N];
    if (tid < H_N) lds_wl[tid] = W_lin[e * H_N + tid];
    __syncthreads();

    const float blin_e = b_lin[e];

    // --- W fragments (A operand), loaded once. wf[hb*3+g]: gate g in {i,g,o},
    // h-block hb in {0,1}. k=13 column carries the bias sum (x supplies 1.0).
    half8 wf[6];
#pragma unroll
    for (int g = 0; g < 3; ++g) {
        const int gbase = (g == 0) ? 0 : (g == 1) ? 2 * H_N : 3 * H_N; // i,g,o (f dead)
#pragma unroll
        for (int hb = 0; hb < 2; ++hb) {
            const int row = gbase + hb * 32 + lrow;
            const float* wr = W_ih + ((size_t)e * G_N + row) * I_N;
            const float bias = b_ih[e * G_N + row] + b_hh[e * G_N + row];
            half8 f;
#pragma unroll
            for (int j = 0; j < 8; ++j) {
                const int k = koff + j;
                const float v = (k < I_N) ? wr[k] : ((k == I_N) ? bias : 0.0f);
                f[j] = (_Float16)v;
            }
            wf[hb * 3 + g] = f;
        }
    }

    const int b_wave = tileb * ROWS_PER_BLOCK + wave * 128;

    // --- prefetch x slice for it=0 (8 floats; k=13 column = 1.0 for bias)
    float xn[8];
    {
        const int br = b_wave + lrow;
        const int bb = (br < n_b) ? br : (n_b - 1);
        const float* xb = x + (size_t)bb * (E_N * I_N) + e * I_N;
#pragma unroll
        for (int j = 0; j < 8; ++j) {
            const int k = koff + j;
            xn[j] = (k < I_N) ? xb[k] : ((k == I_N) ? 1.0f : 0.0f);
        }
    }

#pragma unroll
    for (int it = 0; it < 4; ++it) {
        // issue next iteration's loads BEFORE consuming current (latency hide)
        float xnext[8];
        if (it < 3) {
            const int br = b_wave + (it + 1) * 32 + lrow;
            const int bb = (br < n_b) ? br : (n_b - 1);
            const float* xb = x + (size_t)bb * (E_N * I_N) + e * I_N;
#pragma unroll
            for (int j = 0; j < 8; ++j) {
                const int k = koff + j;
                xnext[j] = (k < I_N) ? xb[k] : ((k == I_N) ? 1.0f : 0.0f);
            }
        }

        // pack current x fragment (B operand: B[k][n], n = batch col = lrow)
        half8 xh;
#pragma unroll
        for (int j = 0; j < 8; ++j) xh[j] = (_Float16)xn[j];

        float partial = 0.0f;
#pragma unroll
        for (int hb = 0; hb < 2; ++hb) {
            f32x16 zz;
#pragma unroll
            for (int q = 0; q < 16; ++q) zz[q] = 0.0f;
            const f32x16 ai = __builtin_amdgcn_mfma_f32_32x32x16_f16(wf[hb * 3 + 0], xh, zz, 0, 0, 0);
            const f32x16 ag = __builtin_amdgcn_mfma_f32_32x32x16_f16(wf[hb * 3 + 1], xh, zz, 0, 0, 0);
            const f32x16 ao = __builtin_amdgcn_mfma_f32_32x32x16_f16(wf[hb * 3 + 2], xh, zz, 0, 0, 0);
#pragma unroll
            for (int r = 0; r < 16; ++r) {
                const int h = hb * 32 + (r & 3) + 8 * (r >> 2) + 4 * khalf;
                // c = sigma(ai)*tanh(ag) with one shared rcp (3 trans not 4)
                const float ei = fast_exp(-ai[r]);
                const float eg = fast_exp(2.0f * ag[r]);
                const float c  = (eg - 1.0f) * fast_rcp((1.0f + ei) * (1.0f + eg));
                // hh = sigma(ao)*tanh(c), same fusion; c in (-1,1) so e^{2c} safe
                const float eo = fast_exp(-ao[r]);
                const float ec = fast_exp(2.0f * c);
                const float hh = (ec - 1.0f) * fast_rcp((1.0f + eo) * (1.0f + ec));
                partial = fmaf(hh, lds_wl[h], partial);
            }
        }

        const float pre = partial + __shfl_xor(partial, 32) + blin_e;
        const int bo = b_wave + it * 32 + lrow;
        if (lane < 32 && bo < n_b)
            out[(size_t)bo * E_N + e] = fast_rcp(1.0f + fast_exp(-pre));

        // rotate prefetch regs (renamed away by full unroll)
#pragma unroll
        for (int j = 0; j < 8; ++j) xn[j] = xnext[j];
    }
}

extern "C" void kernel_launch(void* const* d_in, const int* in_sizes, int n_in,
                              void* d_out, int out_size, void* d_ws, size_t ws_size,
                              hipStream_t stream) {
    const float* x     = (const float*)d_in[0];
    const float* W_ih  = (const float*)d_in[1];
    // d_in[2] = W_hh : dead (h0 = 0)
    const float* b_ih  = (const float*)d_in[3];
    const float* b_hh  = (const float*)d_in[4];
    const float* W_lin = (const float*)d_in[5];
    const float* b_lin = (const float*)d_in[6];
    float* out = (float*)d_out;

    const int n_b = in_sizes[0] / (E_N * I_N);  // 131072
    dim3 grid((n_b + ROWS_PER_BLOCK - 1) / ROWS_PER_BLOCK, E_N);  // (256, 13)

    music_lstm_mfma<<<grid, 256, 0, stream>>>(x, W_ih, b_ih, b_hh, W_lin, b_lin, out, n_b);
}